// Round 1
// baseline (373.758 us; speedup 1.0000x reference)
//
#include <hip/hip_runtime.h>

// B3-spline undecimated wavelet transform (a trous), 3 levels, fused.
// x: (16,1024,1024) f32 -> out: (16,4,1024,1024) f32 = [w1,w2,w3,c3].
// One block = 32x64 output tile. LDS ping-pong A/B (60x96 f32 each, 45KB).
// Reflect handled once at load (kernel symmetric => reflect commutes w/ conv).

#define TXT 64      // tile width  (output cols per block)
#define TYT 32      // tile height (output rows per block)
#define BX 96       // buffer cols = TXT + 16 + 16 (16-col halo for f4-aligned stores)
#define BY 60       // buffer rows = TYT + 14 + 14
#define NCB 24      // BX / 4 (float4 blocks per row)
#define HH 1024
#define WW 1024

__device__ __forceinline__ int reflect_i(int g, int n) {
    if (g < 0) g = -g;
    else if (g >= n) g = 2 * n - 2 - g;
    return g;
}

__device__ constexpr float Kw0 = 1.0f / 16.0f;
__device__ constexpr float Kw1 = 4.0f / 16.0f;
__device__ constexpr float Kw2 = 6.0f / 16.0f;

// H-conv (along rows): reads A, writes B. Each unit = 4 output rows spaced D
// apart at one float4 col-block -> 8 b128 reads, 4 b128 writes.
template <int D, int H0, int NR, int C0B, int NCBH>
__device__ __forceinline__ void hconv(const float4* __restrict__ A4,
                                      float4* __restrict__ B4, int tid) {
    constexpr int NRB = NR / 4;          // row units
    constexpr int CNT = NRB * NCBH;
    for (int u = tid; u < CNT; u += 256) {
        int rb = u / NCBH;
        int cb = C0B + (u - rb * NCBH);
        int base = H0 + (rb % D) + (rb / D) * (4 * D);
        float4 win[8];
#pragma unroll
        for (int j = 0; j < 8; ++j)
            win[j] = A4[(base + (j - 2) * D) * NCB + cb];
#pragma unroll
        for (int t = 0; t < 4; ++t) {
            float4 o;
            o.x = Kw0 * (win[t].x + win[t + 4].x) + Kw1 * (win[t + 1].x + win[t + 3].x) + Kw2 * win[t + 2].x;
            o.y = Kw0 * (win[t].y + win[t + 4].y) + Kw1 * (win[t + 1].y + win[t + 3].y) + Kw2 * win[t + 2].y;
            o.z = Kw0 * (win[t].z + win[t + 4].z) + Kw1 * (win[t + 1].z + win[t + 3].z) + Kw2 * win[t + 2].z;
            o.w = Kw0 * (win[t].w + win[t + 4].w) + Kw1 * (win[t + 1].w + win[t + 3].w) + Kw2 * win[t + 2].w;
            B4[(base + t * D) * NCB + cb] = o;
        }
    }
}

// W-conv (along cols): reads B, writes y_{j+1} into A in place, emits detail
// (old A - new) to global for the tile center. LVL==2 also emits c3.
template <int D, int H0, int NR, int WC0, int NWB, int LVL>
__device__ __forceinline__ void wconv(float4* __restrict__ A4,
                                      const float4* __restrict__ B4,
                                      float* __restrict__ out,
                                      int tx0, int ty0, int bz, int tid) {
    constexpr int CNT = NR * NWB;
    for (int u = tid; u < CNT; u += 256) {
        int ri = u / NWB;
        int wb = u - ri * NWB;
        int r = H0 + ri;
        int c = WC0 + 4 * wb;
        int cb = c >> 2;
        float4 vv[5];
        float* v = (float*)vv;
        const float4* Brow = B4 + r * NCB;
        if (D == 4) {
#pragma unroll
            for (int j = 0; j < 5; ++j) vv[j] = Brow[cb - 2 + j];
        } else {
            vv[1] = Brow[cb - 1];
            vv[2] = Brow[cb];
            vv[3] = Brow[cb + 1];
        }
        float4 o;
#define WCV(p) (Kw0 * (v[(p) - 2 * D] + v[(p) + 2 * D]) + Kw1 * (v[(p) - D] + v[(p) + D]) + Kw2 * v[(p)])
        o.x = WCV(8);
        o.y = WCV(9);
        o.z = WCV(10);
        o.w = WCV(11);
#undef WCV
        float4 old = A4[r * NCB + cb];
        A4[r * NCB + cb] = o;
        float4 det = make_float4(old.x - o.x, old.y - o.y, old.z - o.z, old.w - o.w);
        if (LVL == 2) {
            // full range of this phase IS the center: no guard
            int h = ty0 + r - 14;
            int w = tx0 + c - 16;
            size_t base = ((((size_t)bz) * 4 + 2) * HH + h) * (size_t)WW + w;
            *(float4*)(out + base) = det;                         // w3
            *(float4*)(out + base + (size_t)HH * WW) = o;         // c3
        } else {
            if (r >= 14 && r < 14 + TYT && c >= 16 && c < 16 + TXT) {
                int h = ty0 + r - 14;
                int w = tx0 + c - 16;
                size_t base = ((((size_t)bz) * 4 + LVL) * HH + h) * (size_t)WW + w;
                *(float4*)(out + base) = det;                     // w1 / w2
            }
        }
    }
}

__global__ __launch_bounds__(256) void uwt3_kernel(const float* __restrict__ x,
                                                   float* __restrict__ out) {
    __shared__ float4 A4[BY * NCB];
    __shared__ float4 B4[BY * NCB];

    const int tid = threadIdx.x;
    const int tx0 = blockIdx.x * TXT;
    const int ty0 = blockIdx.y * TYT;
    const int bz = blockIdx.z;
    const float* xb = x + (size_t)bz * HH * WW;

    // ---- load 60x96 region (reflect at image edges), float4 fast path ----
    for (int i = tid; i < BY * NCB; i += 256) {
        int r = i / NCB;
        int cb = i - r * NCB;
        int gr = reflect_i(ty0 + r - 14, HH);
        int w0 = tx0 + 4 * cb - 16;
        float4 val;
        if (w0 >= 0 && w0 + 3 < WW) {
            val = *(const float4*)(xb + (size_t)gr * WW + w0);
        } else {
            float t0 = xb[(size_t)gr * WW + reflect_i(w0 + 0, WW)];
            float t1 = xb[(size_t)gr * WW + reflect_i(w0 + 1, WW)];
            float t2 = xb[(size_t)gr * WW + reflect_i(w0 + 2, WW)];
            float t3 = xb[(size_t)gr * WW + reflect_i(w0 + 3, WW)];
            val = make_float4(t0, t1, t2, t3);
        }
        A4[i] = val;
    }
    __syncthreads();

    // ---- level 1 (d=1): rows [2,58), H cols [0,96), W cols [4,92) ----
    hconv<1, 2, 56, 0, 24>(A4, B4, tid);
    __syncthreads();
    wconv<1, 2, 56, 4, 22, 0>(A4, B4, out, tx0, ty0, bz, tid);
    __syncthreads();

    // ---- level 2 (d=2): rows [6,54), H cols [4,92), W cols [8,88) ----
    hconv<2, 6, 48, 1, 22>(A4, B4, tid);
    __syncthreads();
    wconv<2, 6, 48, 8, 20, 1>(A4, B4, out, tx0, ty0, bz, tid);
    __syncthreads();

    // ---- level 3 (d=4): rows [14,46), H cols [8,88), W cols [16,80) ----
    hconv<4, 14, 32, 2, 20>(A4, B4, tid);
    __syncthreads();
    wconv<4, 14, 32, 16, 16, 2>(A4, B4, out, tx0, ty0, bz, tid);
}

extern "C" void kernel_launch(void* const* d_in, const int* in_sizes, int n_in,
                              void* d_out, int out_size, void* d_ws, size_t ws_size,
                              hipStream_t stream) {
    const float* x = (const float*)d_in[0];
    float* out = (float*)d_out;
    dim3 grid(WW / TXT, HH / TYT, 16);   // 16 x 32 x 16 = 8192 blocks
    uwt3_kernel<<<grid, dim3(256, 1, 1), 0, stream>>>(x, out);
}

// Round 2
// 350.010 us; speedup vs baseline: 1.0678x; 1.0678x over previous
//
#include <hip/hip_runtime.h>

// B3-spline undecimated wavelet transform (a trous), 3 levels, fused, bf16 LDS.
// x: (16,1024,1024) f32 -> out: (16,4,1024,1024) f32 = [w1,w2,w3,c3].
// One block = 32x64 output tile. LDS A/B hold bf16 (60 x 96 cols, stride 104 u16
// = 208 B: 16B-aligned, odd multiple of 128B bank wrap -> no cross-row aliasing).
// All math in f32; only LDS storage is bf16 (threshold 9.5e-2 permits it).

#define HH 1024
#define WW 1024
#define TXT 64      // output cols per block
#define TYT 32      // output rows per block
#define BY 60       // buffer rows = 32 + 14 + 14
#define BXS 104     // row stride in u16 (96 used cols + pad)
#define NC8 12      // 96 cols / 8 per b128

typedef unsigned short u16;
typedef unsigned int u32;

__device__ __forceinline__ int reflect_i(int g, int n) {
    if (g < 0) g = -g;
    else if (g >= n) g = 2 * n - 2 - g;
    return g;
}

__device__ __forceinline__ float bl(u32 u) { return __uint_as_float(u << 16); }
__device__ __forceinline__ float bh(u32 u) { return __uint_as_float(u & 0xffff0000u); }

// pack two f32 -> two bf16 (RNE), a = even (low half), b = odd (high half)
__device__ __forceinline__ u32 pack2(float a, float b) {
    u32 ua = __float_as_uint(a); ua += 0x7fff + ((ua >> 16) & 1);
    u32 ub = __float_as_uint(b); ub += 0x7fff + ((ub >> 16) & 1);
    return (ua >> 16) | (ub & 0xffff0000u);
}

__device__ __forceinline__ void unpack8(uint4 v, float* f) {
    f[0] = bl(v.x); f[1] = bh(v.x);
    f[2] = bl(v.y); f[3] = bh(v.y);
    f[4] = bl(v.z); f[5] = bh(v.z);
    f[6] = bl(v.w); f[7] = bh(v.w);
}

__device__ constexpr float K0 = 1.0f / 16.0f;
__device__ constexpr float K1 = 4.0f / 16.0f;
__device__ constexpr float K2 = 6.0f / 16.0f;

// Vertical 5-tap (dilation D): reads S rows base+(j-2)*D, writes Dst rows
// base..base+3*D (step D). Unit = 4 output rows x 8 cols -> 8 reads, 4 writes.
template <int D, int H0, int NRB>
__device__ __forceinline__ void vpass(const u16* S, u16* Dst, int tid) {
    constexpr int CNT = NRB * NC8;
    for (int u = tid; u < CNT; u += 256) {
        int rb = u / NC8, c8 = u - rb * NC8;
        int base = H0 + (rb % D) + (rb / D) * (4 * D);
        const u16* sp = S + 8 * c8;
        uint4 rv[8];
#pragma unroll
        for (int j = 0; j < 8; ++j)
            rv[j] = *(const uint4*)(sp + (base + (j - 2) * D) * BXS);
        uint4 ov[4];
#pragma unroll
        for (int p = 0; p < 4; ++p) {
            u32 rp[8];
#pragma unroll
            for (int j = 0; j < 8; ++j) rp[j] = ((const u32*)&rv[j])[p];
#pragma unroll
            for (int t = 0; t < 4; ++t) {
                float lo = K0 * (bl(rp[t]) + bl(rp[t + 4])) + K1 * (bl(rp[t + 1]) + bl(rp[t + 3])) + K2 * bl(rp[t + 2]);
                float hi = K0 * (bh(rp[t]) + bh(rp[t + 4])) + K1 * (bh(rp[t + 1]) + bh(rp[t + 3])) + K2 * bh(rp[t + 2]);
                ((u32*)&ov[t])[p] = pack2(lo, hi);
            }
        }
        u16* dp = Dst + 8 * c8;
#pragma unroll
        for (int t = 0; t < 4; ++t)
            *(uint4*)(dp + (base + t * D) * BXS) = ov[t];
    }
}

// Horizontal 5-tap (dilation D) on Bs, in-place update of A (y_j -> y_{j+1}),
// emits detail (old - new) to global; LVL==2 also emits c3.
template <int D, int H0, int NR, int C8LO, int NC, int LVL>
__device__ __forceinline__ void hpass(u16* A, const u16* Bs, float* __restrict__ out,
                                      int tx0, int ty0, int bz, int tid) {
    constexpr int CNT = NR * NC;
    for (int u = tid; u < CNT; u += 256) {
        int ri = u / NC, ci = u - ri * NC;
        int c8 = C8LO + ci, r = H0 + ri;
        const u16* br = Bs + r * BXS;
        int cm = (c8 > 0 ? c8 - 1 : 0);
        int cp = (c8 < NC8 - 1 ? c8 + 1 : NC8 - 1);
        float v[24];
        unpack8(*(const uint4*)(br + 8 * cm), v);
        unpack8(*(const uint4*)(br + 8 * c8), v + 8);
        unpack8(*(const uint4*)(br + 8 * cp), v + 16);
        float o[8];
#pragma unroll
        for (int i = 0; i < 8; ++i)
            o[i] = K0 * (v[8 + i - 2 * D] + v[8 + i + 2 * D]) + K1 * (v[8 + i - D] + v[8 + i + D]) + K2 * v[8 + i];
        u16* ap = A + r * BXS + 8 * c8;
        float old[8];
        unpack8(*(const uint4*)ap, old);
        uint4 nv;
        nv.x = pack2(o[0], o[1]); nv.y = pack2(o[2], o[3]);
        nv.z = pack2(o[4], o[5]); nv.w = pack2(o[6], o[7]);
        *(uint4*)ap = nv;
        bool st = (LVL == 2) || (r >= 14 && r < 46 && c8 >= 2 && c8 < 10);
        if (st) {
            int h = ty0 + r - 14, w = tx0 + 8 * c8 - 16;
            size_t base = ((((size_t)bz) * 4 + LVL) * HH + h) * (size_t)WW + w;
            *(float4*)(out + base)     = make_float4(old[0] - o[0], old[1] - o[1], old[2] - o[2], old[3] - o[3]);
            *(float4*)(out + base + 4) = make_float4(old[4] - o[4], old[5] - o[5], old[6] - o[6], old[7] - o[7]);
            if (LVL == 2) {
                size_t cbase = base + (size_t)HH * WW;
                *(float4*)(out + cbase)     = make_float4(o[0], o[1], o[2], o[3]);
                *(float4*)(out + cbase + 4) = make_float4(o[4], o[5], o[6], o[7]);
            }
        }
    }
}

__global__ __launch_bounds__(256) void uwt3_bf16(const float* __restrict__ x,
                                                 float* __restrict__ out) {
    __shared__ u16 A[BY * BXS];
    __shared__ u16 Bs[BY * BXS];
    const int tid = threadIdx.x;
    const int tx0 = blockIdx.x * TXT;
    const int ty0 = blockIdx.y * TYT;
    const int bz = blockIdx.z;
    const float* xb = x + (size_t)bz * HH * WW;

    // ---- load 60 rows x 96 cols (reflect at edges), f32 -> bf16 ----
    for (int i = tid; i < BY * NC8; i += 256) {
        int r = i / NC8, c8 = i - r * NC8;
        int gr = reflect_i(ty0 + r - 14, HH);
        int w0 = tx0 + 8 * c8 - 16;
        const float* row = xb + (size_t)gr * WW;
        float f[8];
        if (w0 >= 0 && w0 + 7 < WW) {
            float4 a = *(const float4*)(row + w0);
            float4 b = *(const float4*)(row + w0 + 4);
            f[0] = a.x; f[1] = a.y; f[2] = a.z; f[3] = a.w;
            f[4] = b.x; f[5] = b.y; f[6] = b.z; f[7] = b.w;
        } else {
#pragma unroll
            for (int k = 0; k < 8; ++k) f[k] = row[reflect_i(w0 + k, WW)];
        }
        uint4 v;
        v.x = pack2(f[0], f[1]); v.y = pack2(f[2], f[3]);
        v.z = pack2(f[4], f[5]); v.w = pack2(f[6], f[7]);
        *(uint4*)(A + r * BXS + 8 * c8) = v;
    }
    __syncthreads();

    // level 1 (d=1): rows [2,58), h-out cols full width (garbage edges unused)
    vpass<1, 2, 14>(A, Bs, tid);
    __syncthreads();
    hpass<1, 2, 56, 0, 12, 0>(A, Bs, out, tx0, ty0, bz, tid);
    __syncthreads();

    // level 2 (d=2): rows [6,54), h-out blocks 1..10 (cols [8,88))
    vpass<2, 6, 12>(A, Bs, tid);
    __syncthreads();
    hpass<2, 6, 48, 1, 10, 1>(A, Bs, out, tx0, ty0, bz, tid);
    __syncthreads();

    // level 3 (d=4): rows [14,46), h-out blocks 2..9 (cols [16,80)) = center
    vpass<4, 14, 8>(A, Bs, tid);
    __syncthreads();
    hpass<4, 14, 32, 2, 8, 2>(A, Bs, out, tx0, ty0, bz, tid);
}

extern "C" void kernel_launch(void* const* d_in, const int* in_sizes, int n_in,
                              void* d_out, int out_size, void* d_ws, size_t ws_size,
                              hipStream_t stream) {
    const float* x = (const float*)d_in[0];
    float* out = (float*)d_out;
    dim3 grid(WW / TXT, HH / TYT, 16);  // 16 x 32 x 16 = 8192 blocks
    uwt3_bf16<<<grid, dim3(256, 1, 1), 0, stream>>>(x, out);
}